// Round 14
// baseline (1198.689 us; speedup 1.0000x reference)
//
#include <hip/hip_runtime.h>
#include <hip/hip_bf16.h>
#include <math.h>

namespace {

constexpr int B = 4, T = 1024, C = 1024, Hh = 16, L = 2, E = 8, HD = 64;
constexpr int NTOK = B * T;          // 4096
constexpr int CAP = 1024;            // B*T*K/E
constexpr int C3 = 3 * C, C4 = 4 * C;

typedef __attribute__((ext_vector_type(8))) short bf16x8;
typedef __attribute__((ext_vector_type(8))) short short8;
typedef __attribute__((ext_vector_type(4))) float f32x4;

static __device__ __forceinline__ short f2b(float f) {
  __hip_bfloat16 h = __float2bfloat16(f);
  return *reinterpret_cast<short*>(&h);
}
static __device__ __forceinline__ float b2f(unsigned short u) {
  union { unsigned int i; float f; } v; v.i = (unsigned int)u << 16; return v.f;
}
static __device__ __forceinline__ bf16x8 pack8(float4 a, float4 b) {
  bf16x8 r;
  r[0] = f2b(a.x); r[1] = f2b(a.y); r[2] = f2b(a.z); r[3] = f2b(a.w);
  r[4] = f2b(b.x); r[5] = f2b(b.y); r[6] = f2b(b.z); r[7] = f2b(b.w);
  return r;
}

// swizzled byte offset within a tile of 128-byte rows (128^2 kernel / attn)
#define SWZ(row, kb) (((row) << 7) + ((kb) ^ (((row) & 7) << 4)))

static __device__ __forceinline__ void gload16(const void* g, void* l) {
  __builtin_amdgcn_global_load_lds((const __attribute__((address_space(1))) void*)g,
                                   (__attribute__((address_space(3))) void*)l, 16, 0, 0);
}

// ---------------- fp32 -> bf16 convert (qkv_w + out_w only), one-shot ----------------
__global__ __launch_bounds__(256) void cvt2_kernel(
    const float* __restrict__ s0, const float* __restrict__ s1,
    unsigned short* __restrict__ d0, unsigned short* __restrict__ d1) {
  constexpr size_t N0 = (size_t)L * C3 * C;
  size_t i = ((size_t)blockIdx.x * 256 + threadIdx.x) * 16;
  const float* s; unsigned short* d; size_t off;
  if (i < N0) { s = s0; d = d0; off = i; }
  else        { s = s1; d = d1; off = i - N0; }
  float4 v0 = *(const float4*)(s + off);
  float4 v1 = *(const float4*)(s + off + 4);
  float4 v2 = *(const float4*)(s + off + 8);
  float4 v3 = *(const float4*)(s + off + 12);
  short8 r0, r1;
  r0[0] = f2b(v0.x); r0[1] = f2b(v0.y); r0[2] = f2b(v0.z); r0[3] = f2b(v0.w);
  r0[4] = f2b(v1.x); r0[5] = f2b(v1.y); r0[6] = f2b(v1.z); r0[7] = f2b(v1.w);
  r1[0] = f2b(v2.x); r1[1] = f2b(v2.y); r1[2] = f2b(v2.z); r1[3] = f2b(v2.w);
  r1[4] = f2b(v3.x); r1[5] = f2b(v3.y); r1[6] = f2b(v3.z); r1[7] = f2b(v3.w);
  *(short8*)(d + off) = r0;
  *(short8*)(d + off + 8) = r1;
}

// ------- fused embedding + ln1 (layer 0) -------
__global__ __launch_bounds__(256) void embed_ln_kernel(const int* __restrict__ ids,
    const float* __restrict__ tok, const float* __restrict__ pos,
    float* __restrict__ x, unsigned short* __restrict__ outb,
    const float* __restrict__ w, const float* __restrict__ b) {
  __shared__ float red[8];
  int row = blockIdx.x, tid = threadIdx.x;
  int t = row & (T - 1);
  int id = ids[row];
  float4 a = ((const float4*)(tok + (size_t)id * C))[tid];
  float4 p = ((const float4*)(pos + (size_t)t * C))[tid];
  float4 v{a.x + p.x, a.y + p.y, a.z + p.z, a.w + p.w};
  ((float4*)(x + (size_t)row * C))[tid] = v;
  float s = v.x + v.y + v.z + v.w;
  #pragma unroll
  for (int off = 32; off > 0; off >>= 1) s += __shfl_down(s, off);
  if ((tid & 63) == 0) red[tid >> 6] = s;
  __syncthreads();
  float mean = (red[0] + red[1] + red[2] + red[3]) * (1.f / C);
  __syncthreads();
  float dx = v.x - mean, dy = v.y - mean, dz = v.z - mean, dw = v.w - mean;
  float sq = dx * dx + dy * dy + dz * dz + dw * dw;
  #pragma unroll
  for (int off = 32; off > 0; off >>= 1) sq += __shfl_down(sq, off);
  if ((tid & 63) == 0) red[tid >> 6] = sq;
  __syncthreads();
  float var = (red[0] + red[1] + red[2] + red[3]) * (1.f / C);
  float rs = rsqrtf(var + 1e-5f);
  float4 wc = ((const float4*)w)[tid];
  float4 bc = ((const float4*)b)[tid];
  short4 ob{f2b(dx * rs * wc.x + bc.x), f2b(dy * rs * wc.y + bc.y),
            f2b(dz * rs * wc.z + bc.z), f2b(dw * rs * wc.w + bc.w)};
  *(short4*)(outb + (size_t)row * C + tid * 4) = ob;
}

// ------- layernorm with optional fused MoE-combine (ln1 l>0 / lnf) ----
__global__ __launch_bounds__(256) void ln_kernel(const float* __restrict__ in,
    const unsigned short* __restrict__ eo, const int* __restrict__ slot0,
    const int* __restrict__ slot1, float* __restrict__ xupd,
    float* __restrict__ out, unsigned short* __restrict__ outb,
    const float* __restrict__ w, const float* __restrict__ b) {
  constexpr size_t SLICE = (size_t)E * CAP * C;
  __shared__ float red[8];
  int row = blockIdx.x, tid = threadIdx.x;
  float4 v = ((const float4*)(in + (size_t)row * C))[tid];
  if (eo) {
    int s0 = slot0[row], s1 = slot1[row];
    auto addslot = [&](int s) {
      if (s < 0) return;
      const unsigned short* p0 = eo + (size_t)s * C + tid * 4;
      short4 u = *(const short4*)p0;
      short4 u2 = *(const short4*)(p0 + SLICE);
      v.x += b2f((unsigned short)u.x) + b2f((unsigned short)u2.x);
      v.y += b2f((unsigned short)u.y) + b2f((unsigned short)u2.y);
      v.z += b2f((unsigned short)u.z) + b2f((unsigned short)u2.z);
      v.w += b2f((unsigned short)u.w) + b2f((unsigned short)u2.w);
    };
    addslot(s0);
    addslot(s1);
    if (xupd) ((float4*)(xupd + (size_t)row * C))[tid] = v;
  }
  float s = v.x + v.y + v.z + v.w;
  #pragma unroll
  for (int off = 32; off > 0; off >>= 1) s += __shfl_down(s, off);
  if ((tid & 63) == 0) red[tid >> 6] = s;
  __syncthreads();
  float mean = (red[0] + red[1] + red[2] + red[3]) * (1.f / C);
  __syncthreads();
  float dx = v.x - mean, dy = v.y - mean, dz = v.z - mean, dw = v.w - mean;
  float sq = dx * dx + dy * dy + dz * dz + dw * dw;
  #pragma unroll
  for (int off = 32; off > 0; off >>= 1) sq += __shfl_down(sq, off);
  if ((tid & 63) == 0) red[tid >> 6] = sq;
  __syncthreads();
  float var = (red[0] + red[1] + red[2] + red[3]) * (1.f / C);
  float rs = rsqrtf(var + 1e-5f);
  float4 wc = ((const float4*)w)[tid];
  float4 bc = ((const float4*)b)[tid];
  float4 o{dx * rs * wc.x + bc.x, dy * rs * wc.y + bc.y,
           dz * rs * wc.z + bc.z, dw * rs * wc.w + bc.w};
  if (out) ((float4*)(out + (size_t)row * C))[tid] = o;
  if (outb) {
    short4 ob{f2b(o.x), f2b(o.y), f2b(o.z), f2b(o.w)};
    *(short4*)(outb + (size_t)row * C + tid * 4) = ob;
  }
}

// ------- fused ln2 + router ----
__global__ __launch_bounds__(256) void ln2_router_kernel(const float* __restrict__ in,
    unsigned short* __restrict__ outb,
    const float* __restrict__ w, const float* __restrict__ b,
    const float* __restrict__ rt_w, const float* __restrict__ rt_b,
    const float* __restrict__ nz_w, const float* __restrict__ nz_b,
    const float* __restrict__ noise,
    int* __restrict__ i0, int* __restrict__ i1, float* __restrict__ g0,
    float* __restrict__ g1, int* __restrict__ slot0, int* __restrict__ slot1)
{
  __shared__ float red[8];
  __shared__ float racc[4][16];
  int row = blockIdx.x, tid = threadIdx.x;
  float4 v = ((const float4*)(in + (size_t)row * C))[tid];
  float s = v.x + v.y + v.z + v.w;
  #pragma unroll
  for (int off = 32; off > 0; off >>= 1) s += __shfl_down(s, off);
  if ((tid & 63) == 0) red[tid >> 6] = s;
  __syncthreads();
  float mean = (red[0] + red[1] + red[2] + red[3]) * (1.f / C);
  __syncthreads();
  float dx = v.x - mean, dy = v.y - mean, dz = v.z - mean, dw = v.w - mean;
  float sq = dx * dx + dy * dy + dz * dz + dw * dw;
  #pragma unroll
  for (int off = 32; off > 0; off >>= 1) sq += __shfl_down(sq, off);
  if ((tid & 63) == 0) red[tid >> 6] = sq;
  __syncthreads();
  float var = (red[0] + red[1] + red[2] + red[3]) * (1.f / C);
  float rs = rsqrtf(var + 1e-5f);
  float4 wc = ((const float4*)w)[tid];
  float4 bc = ((const float4*)b)[tid];
  float4 o{dx * rs * wc.x + bc.x, dy * rs * wc.y + bc.y,
           dz * rs * wc.z + bc.z, dw * rs * wc.w + bc.w};
  short4 ob{f2b(o.x), f2b(o.y), f2b(o.z), f2b(o.w)};
  *(short4*)(outb + (size_t)row * C + tid * 4) = ob;

  float loc[16];
  #pragma unroll
  for (int e = 0; e < 8; e++) {
    float4 rw = *(const float4*)(rt_w + (size_t)e * C + tid * 4);
    float4 nw = *(const float4*)(nz_w + (size_t)e * C + tid * 4);
    loc[e]     = o.x * rw.x + o.y * rw.y + o.z * rw.z + o.w * rw.w;
    loc[8 + e] = o.x * nw.x + o.y * nw.y + o.z * nw.z + o.w * nw.w;
  }
  #pragma unroll
  for (int e = 0; e < 16; e++) {
    #pragma unroll
    for (int off = 32; off > 0; off >>= 1) loc[e] += __shfl_down(loc[e], off);
  }
  if ((tid & 63) == 0) {
    #pragma unroll
    for (int e = 0; e < 16; e++) racc[tid >> 6][e] = loc[e];
  }
  __syncthreads();
  if (tid == 0) {
    float nv[8];
    #pragma unroll
    for (int e = 0; e < 8; e++) {
      float lgt = racc[0][e] + racc[1][e] + racc[2][e] + racc[3][e] + rt_b[e];
      float nl = racc[0][8 + e] + racc[1][8 + e] + racc[2][8 + e] + racc[3][8 + e] + nz_b[e];
      float sp = fmaxf(nl, 0.f) + log1pf(expf(-fabsf(nl)));
      nv[e] = lgt + noise[(size_t)row * E + e] * sp;
    }
    float v0 = -INFINITY, v1 = -INFINITY; int b0 = -1, b1 = -1;
    #pragma unroll
    for (int e = 0; e < 8; e++) {
      float vv = nv[e];
      if (vv > v0)      { v1 = v0; b1 = b0; v0 = vv; b0 = e; }
      else if (vv > v1) { v1 = vv; b1 = e; }
    }
    float ex = expf(v1 - v0);
    float inv = 1.f / (1.f + ex);
    i0[row] = b0; i1[row] = b1;
    g0[row] = inv; g1[row] = ex * inv;
    slot0[row] = -1; slot1[row] = -1;
  }
}

// ============ 256x256 8-phase bf16 MFMA GEMM (QKV) ============
template<bool GATHER, bool RELU, bool BIAS, bool XCDMAP, int OUTMODE, int SPLITK>
__global__ __launch_bounds__(512, 2) void gemm8p(
    const unsigned short* __restrict__ A, const unsigned short* __restrict__ W,
    const float* __restrict__ bias, unsigned short* __restrict__ Cout,
    const int* __restrict__ rowidx, const float* __restrict__ rowscale,
    const int* __restrict__ cnts, int M, int N, int Kd,
    size_t strideA, size_t strideW, size_t strideOut, int strideBias, int GY)
{
  __shared__ alignas(16) char smem[131072];
  int bx, by, e, ksl;
  if constexpr (XCDMAP) {
    int fid = blockIdx.x; e = fid & 7; int r1 = fid >> 3;
    ksl = r1 & (SPLITK - 1); int wi = r1 / SPLITK;
    by = wi % GY; bx = wi / GY;
  } else { bx = blockIdx.x; by = blockIdx.y; e = 0; ksl = 0; }
  int Mr = M;
  if (cnts) { int cc = cnts[e]; Mr = cc < M ? cc : M; }
  int row0 = by * 256, col0 = bx * 256;
  if (row0 >= Mr) return;

  const int kLen = Kd / SPLITK;
  const unsigned short* Ap = A + (size_t)e * strideA;
  const unsigned short* Wp = W + (size_t)e * strideW;
  const int* ridx = rowidx ? rowidx + (size_t)e * CAP : nullptr;

  int t = threadIdx.x;
  int l = t & 63, lm = l & 15, lg = l >> 4;
  int w = t >> 6, wm = w >> 2, wn = w & 3;

  const char* srcA[2];
  const char* srcB[2];
  #pragma unroll
  for (int j = 0; j < 2; j++) {
    int flat = t + j * 512;
    int row = flat >> 2;
    int c16 = (flat & 3) ^ ((row >> 1) & 3);
    int ga;
    if constexpr (GATHER) {
      int ar = row0 + row; if (ar >= Mr) ar = Mr - 1; ga = ridx[ar];
    } else ga = row0 + row;
    srcA[j] = (const char*)Ap + (size_t)ga * Kd * 2 + (size_t)ksl * kLen * 2 + c16 * 16;
    srcB[j] = (const char*)Wp + (size_t)(col0 + row) * Kd * 2 + (size_t)ksl * kLen * 2 + c16 * 16;
  }
  int dst0 = t * 16, dst1 = t * 16 + 8192;

  auto STAGE = [&](int buf, int op, int kh, int kt) {
    size_t goff = (size_t)kt * 128 + kh * 64;
    char* base = smem + buf * 65536 + op * 32768 + kh * 16384;
    if (op) {
      gload16(srcB[0] + goff, base + dst0);
      gload16(srcB[1] + goff, base + dst1);
    } else {
      gload16(srcA[0] + goff, base + dst0);
      gload16(srcA[1] + goff, base + dst1);
    }
  };

  int colswz = (lg ^ ((lm >> 1) & 3)) * 16;

  f32x4 acc[8][4];
  #pragma unroll
  for (int i = 0; i < 8; i++)
    #pragma unroll
    for (int j = 0; j < 4; j++) acc[i][j] = f32x4{0.f, 0.f, 0.f, 0.f};

  STAGE(0, 0, 0, 0); STAGE(0, 1, 0, 0); STAGE(0, 0, 1, 0); STAGE(0, 1, 1, 0);
  asm volatile("s_waitcnt vmcnt(0)" ::: "memory");
  __builtin_amdgcn_s_barrier();

  int NT = kLen >> 6;
  bf16x8 bfr[4];
  for (int k = 0; k < NT; k++) {
    int cur = k & 1, nxt = cur ^ 1;
    bool pf = (k + 1 < NT);
    #pragma unroll
    for (int ph = 0; ph < 4; ph++) {
      const int ks = ph >> 1, mh = ph & 1;
      bf16x8 afr[4];
      #pragma unroll
      for (int i = 0; i < 4; i++) {
        int row = wm * 128 + (mh * 4 + i) * 16 + lm;
        afr[i] = *(const bf16x8*)(smem + cur * 65536 + ks * 16384 + row * 64 + colswz);
      }
      if (mh == 0) {
        #pragma unroll
        for (int i = 0; i < 4; i++) {
          int row = wn * 64 + i * 16 + lm;
          bfr[i] = *(const bf16x8*)(smem + cur * 65536 + 32768 + ks * 16384 + row * 64 + colswz);
        }
      }
      if (pf) STAGE(nxt, mh, ks, k + 1);
      if (mh == 1) {
        if (pf) asm volatile("s_waitcnt vmcnt(4)" ::: "memory");
        else    asm volatile("s_waitcnt vmcnt(0)" ::: "memory");
      }
      __builtin_amdgcn_s_barrier();
      __builtin_amdgcn_s_setprio(1);
      #pragma unroll
      for (int i = 0; i < 4; i++)
        #pragma unroll
        for (int ni = 0; ni < 4; ni++)
          acc[mh * 4 + i][ni] =
              __builtin_amdgcn_mfma_f32_16x16x32_bf16(afr[i], bfr[ni], acc[mh * 4 + i][ni], 0, 0, 0);
      __builtin_amdgcn_s_setprio(0);
      __builtin_amdgcn_s_barrier();
    }
  }

  float cbias[4];
  #pragma unroll
  for (int ni = 0; ni < 4; ni++)
    cbias[ni] = (BIAS && ksl == 0) ? bias[(size_t)e * strideBias + col0 + wn * 64 + ni * 16 + lm] : 0.f;

  #pragma unroll
  for (int mi = 0; mi < 8; mi++) {
    #pragma unroll
    for (int rr = 0; rr < 4; rr++) {
      int m = row0 + wm * 128 + mi * 16 + lg * 4 + rr;
      if (m >= Mr) continue;
      if constexpr (OUTMODE == 0) {
        unsigned short* cp = Cout + (size_t)e * strideOut + (size_t)m * N + col0 + wn * 64 + lm;
        #pragma unroll
        for (int ni = 0; ni < 4; ni++) {
          float v = acc[mi][ni][rr] + cbias[ni];
          if constexpr (RELU) v = fmaxf(v, 0.f);
          cp[ni * 16] = (unsigned short)f2b(v);
        }
      } else {
        float sc = rowscale[(size_t)e * CAP + m];
        unsigned short* cp = Cout + (size_t)ksl * ((size_t)E * CAP * N)
                             + ((size_t)e * CAP + m) * N + col0 + wn * 64 + lm;
        #pragma unroll
        for (int ni = 0; ni < 4; ni++) {
          float v = acc[mi][ni][rr] + cbias[ni];
          cp[ni * 16] = (unsigned short)f2b(sc * v);
        }
      }
    }
  }
}

// ==== 128x256 8-phase GEMM; A bf16 via gload_lds, W fp32 via depth-2 reg banks + cvt ====
// 512 thr = 8 waves (2M x 4N); per-wave 64x64 (acc 64 VGPR). LDS 96KB: per buf
// {A[kh][128][64B] 2x8KB, B[kh][256][64B] 2x16KB}. Counted vmcnt(8) preserved via
// depth-2 W banks (issue order: W(k+1)[prev] < A(k+1)@ph0 < W(k+2)@ph1).
template<bool GATHER, bool RELU, bool BIAS, int OUTMODE, int SPLITK>
__global__ __launch_bounds__(512, 2) void gemm_wf32(
    const unsigned short* __restrict__ A, const float* __restrict__ W,
    const float* __restrict__ bias, unsigned short* __restrict__ Cout,
    const int* __restrict__ rowidx, const float* __restrict__ rowscale,
    const int* __restrict__ cnts, int M, int N, int Kd,
    size_t strideA, size_t strideW, size_t strideOut, int strideBias, int GY)
{
  __shared__ alignas(16) char smem[98304];
  int fid = blockIdx.x;
  int e = fid & 7; int r1 = fid >> 3;
  int ksl = r1 & (SPLITK - 1); int wi = r1 / SPLITK;
  int by = wi % GY, bx = wi / GY;
  int Mr = M;
  if (cnts) { int cc = cnts[e]; Mr = cc < M ? cc : M; }
  int row0 = by * 128, col0 = bx * 256;
  if (row0 >= Mr) return;

  const int kLen = Kd / SPLITK;   // NT = kLen/64 is even (16 or 32)
  const unsigned short* Ap = A + (size_t)e * strideA;
  const float* Wp = W + (size_t)e * strideW;
  const int* ridx = rowidx ? rowidx + (size_t)e * CAP : nullptr;

  int t = threadIdx.x;
  int l = t & 63, lm = l & 15, lg = l >> 4;
  int w = t >> 6, wm = w >> 2, wn = w & 3;    // wm 0..1, wn 0..3

  // ---- A staging (bf16 gload_lds, pre-swizzled source) ----
  int arow = t >> 2;
  int ac16 = (t & 3) ^ ((arow >> 1) & 3);
  int aga;
  if constexpr (GATHER) {
    int ar = row0 + arow; if (ar >= Mr) ar = Mr - 1; aga = ridx[ar];
  } else aga = row0 + arow;
  const char* srcA = (const char*)Ap + (size_t)aga * Kd * 2 + (size_t)ksl * kLen * 2 + ac16 * 16;
  int adst = t * 16;
  auto STAGEA = [&](int buf, int kt) {       // 2 gload16 (kh0, kh1)
    size_t g = (size_t)kt * 128;
    char* base = smem + buf * 49152;
    gload16(srcA + g, base + adst);
    gload16(srcA + g + 64, base + 8192 + adst);
  };

  // ---- W fp32 staging: depth-2 named banks -> bf16 swizzled ds_write ----
  int brow = t >> 1;            // 0..255
  int bh2 = t & 1;              // which K-half this thread covers
  const float* bsrc = Wp + (size_t)(col0 + brow) * Kd + (size_t)ksl * kLen + bh2 * 32;
  int bxor = ((brow >> 1) & 3) ^ (bh2 << 1);
  float4 bregA[8], bregB[8];
  auto LOADB_A = [&](int kt) {
    const float* p = bsrc + (size_t)kt * 64;
    #pragma unroll
    for (int i = 0; i < 8; i++) bregA[i] = *(const float4*)(p + i * 4);
  };
  auto LOADB_B = [&](int kt) {
    const float* p = bsrc + (size_t)kt * 64;
    #pragma unroll
    for (int i = 0; i < 8; i++) bregB[i] = *(const float4*)(p + i * 4);
  };
  auto WRITEB_A = [&](int buf) {
    char* base = smem + buf * 49152 + 16384 + bh2 * 16384 + brow * 64;
    #pragma unroll
    for (int j = 0; j < 4; j++)
      *(bf16x8*)(base + ((j ^ bxor) * 16)) = pack8(bregA[2 * j], bregA[2 * j + 1]);
  };
  auto WRITEB_B = [&](int buf) {
    char* base = smem + buf * 49152 + 16384 + bh2 * 16384 + brow * 64;
    #pragma unroll
    for (int j = 0; j < 4; j++)
      *(bf16x8*)(base + ((j ^ bxor) * 16)) = pack8(bregB[2 * j], bregB[2 * j + 1]);
  };

  int aswz = (lg ^ ((lm >> 1) & 3)) * 16;

  f32x4 acc[4][4];
  #pragma unroll
  for (int i = 0; i < 4; i++)
    #pragma unroll
    for (int j = 0; j < 4; j++) acc[i][j] = f32x4{0.f, 0.f, 0.f, 0.f};

  int NT = kLen >> 6;

  // prologue: W(0)->bankA, A(0)->buf0, W(1)->bankB, write W(0)->buf0
  LOADB_A(0);
  STAGEA(0, 0);
  LOADB_B(1);
  WRITEB_A(0);                                          // implicit wait drains W(0)
  asm volatile("s_waitcnt vmcnt(8)" ::: "memory");      // A(0) landed; W(1) in flight
  asm volatile("s_waitcnt lgkmcnt(0)" ::: "memory");
  __builtin_amdgcn_s_barrier();

  bf16x8 bfr[4];
  auto TILE = [&](int cbase, auto stage_fn, auto write_fn) {
    #pragma unroll
    for (int ph = 0; ph < 4; ph++) {
      const int ks = ph >> 1, mh = ph & 1;
      bf16x8 afr[2];
      #pragma unroll
      for (int i = 0; i < 2; i++) {
        int row = wm * 64 + (mh * 2 + i) * 16 + lm;
        afr[i] = *(const bf16x8*)(smem + cbase + ks * 8192 + row * 64 + aswz);
      }
      if (mh == 0) {
        int bswz = ((lg ^ ((lm >> 1) & 3)) ^ (ks << 1)) * 16;
        #pragma unroll
        for (int i = 0; i < 4; i++) {
          int row = wn * 64 + i * 16 + lm;
          bfr[i] = *(const bf16x8*)(smem + cbase + 16384 + ks * 16384 + row * 64 + bswz);
        }
      }
      stage_fn(ph);
      if (ph == 3) write_fn();
      __builtin_amdgcn_s_barrier();
      __builtin_amdgcn_s_setprio(1);
      #pragma unroll
      for (int i = 0; i < 2; i++)
        #pragma unroll
        for (int ni = 0; ni < 4; ni++)
          acc[mh * 2 + i][ni] =
              __builtin_amdgcn_mfma_f32_16x16x32_bf16(afr[i], bfr[ni], acc[mh * 2 + i][ni], 0, 0, 0);
      __builtin_amdgcn_s_setprio(0);
      __builtin_amdgcn_s_barrier();
    }
  };

  for (int k = 0; k < NT; k += 2) {
    bool pf2 = (k + 2 < NT);
    bool pf3 = (k + 3 < NT);
    // tile k (buf0): stage A(k+1)->buf1, W(k+2)->bankA, write W(k+1)(bankB)->buf1
    TILE(0,
      [&](int ph) {
        if (ph == 0) STAGEA(1, k + 1);
        if (ph == 1 && pf2) LOADB_A(k + 2);
      },
      [&]() {
        WRITEB_B(1);                                    // drains W(k+1)
        if (pf2) asm volatile("s_waitcnt vmcnt(8)" ::: "memory");
        else     asm volatile("s_waitcnt vmcnt(0)" ::: "memory");
        asm volatile("s_waitcnt lgkmcnt(0)" ::: "memory");
      });
    // tile k+1 (buf1): stage A(k+2)->buf0, W(k+3)->bankB, write W(k+2)(bankA)->buf0
    TILE(49152,
      [&](int ph) {
        if (ph == 0 && pf2) STAGEA(0, k + 2);
        if (ph == 1 && pf3) LOADB_B(k + 3);
      },
      [&]() {
        if (pf2) {
          WRITEB_A(0);
          if (pf3) asm volatile("s_waitcnt vmcnt(8)" ::: "memory");
          else     asm volatile("s_waitcnt vmcnt(0)" ::: "memory");
          asm volatile("s_waitcnt lgkmcnt(0)" ::: "memory");
        }
      });
  }

  // epilogue
  float cbias[4];
  #pragma unroll
  for (int ni = 0; ni < 4; ni++)
    cbias[ni] = (BIAS && ksl == 0) ? bias[(size_t)e * strideBias + col0 + wn * 64 + ni * 16 + lm] : 0.f;

  #pragma unroll
  for (int mi = 0; mi < 4; mi++) {
    #pragma unroll
    for (int rr = 0; rr < 4; rr++) {
      int m = row0 + wm * 64 + mi * 16 + lg * 4 + rr;
      if (m >= Mr) continue;
      if constexpr (OUTMODE == 0) {
        unsigned short* cp = Cout + (size_t)e * strideOut + (size_t)m * N + col0 + wn * 64 + lm;
        #pragma unroll
        for (int ni = 0; ni < 4; ni++) {
          float v = acc[mi][ni][rr] + cbias[ni];
          if constexpr (RELU) v = fmaxf(v, 0.f);
          cp[ni * 16] = (unsigned short)f2b(v);
        }
      } else {
        float sc = rowscale[(size_t)e * CAP + m];
        unsigned short* cp = Cout + (size_t)ksl * ((size_t)E * CAP * N)
                             + ((size_t)e * CAP + m) * N + col0 + wn * 64 + lm;
        #pragma unroll
        for (int ni = 0; ni < 4; ni++) {
          float v = acc[mi][ni][rr] + cbias[ni];
          cp[ni * 16] = (unsigned short)f2b(sc * v);
        }
      }
    }
  }
}

// ---------------- 128^2 bf16 MFMA GEMM (proj, fp32 residual accumulate) ----------------
__global__ __launch_bounds__(256) void gemm_proj(
    const unsigned short* __restrict__ A, const unsigned short* __restrict__ W,
    float* __restrict__ Cout, int M, int N, int Kd)
{
  int bx = blockIdx.x, by = blockIdx.y;
  int row0 = by * 128, col0 = bx * 128;

  __shared__ alignas(16) char smem[32768];
  char* Ab = smem;
  char* Bb = smem + 16384;

  int t = threadIdx.x, w = t >> 6, l = t & 63;
  int lm = l & 15, lg = l >> 4;
  int wr = w >> 1, wc = w & 1;

  int lrow8 = l >> 3;
  int scol = ((l & 7) ^ lrow8) << 4;
  const char* srcA[4];
  const char* srcB[4];
  #pragma unroll
  for (int i = 0; i < 4; i++) {
    int seg = w * 4 + i;
    int rloc = seg * 8 + lrow8;
    srcA[i] = (const char*)A + (size_t)(row0 + rloc) * Kd * 2 + scol;
    srcB[i] = (const char*)W + (size_t)(col0 + rloc) * Kd * 2 + scol;
  }

  f32x4 acc[4][4];
  #pragma unroll
  for (int i = 0; i < 4; i++)
    #pragma unroll
    for (int j = 0; j < 4; j++) acc[i][j] = f32x4{0.f, 0.f, 0.f, 0.f};

  int NT = Kd >> 6;
  for (int kt = 0; kt < NT; kt++) {
    __syncthreads();
    #pragma unroll
    for (int i = 0; i < 4; i++) {
      int seg = w * 4 + i;
      gload16(srcA[i], Ab + seg * 1024);
      gload16(srcB[i], Bb + seg * 1024);
      srcA[i] += 128;
      srcB[i] += 128;
    }
    __syncthreads();
    #pragma unroll
    for (int ks = 0; ks < 2; ks++) {
      bf16x8 af[4], bfr[4];
      #pragma unroll
      for (int mi = 0; mi < 4; mi++)
        af[mi] = *(const bf16x8*)(Ab + SWZ(wr * 64 + mi * 16 + lm, ks * 64 + lg * 16));
      #pragma unroll
      for (int ni = 0; ni < 4; ni++)
        bfr[ni] = *(const bf16x8*)(Bb + SWZ(wc * 64 + ni * 16 + lm, ks * 64 + lg * 16));
      #pragma unroll
      for (int mi = 0; mi < 4; mi++)
        #pragma unroll
        for (int ni = 0; ni < 4; ni++)
          acc[mi][ni] = __builtin_amdgcn_mfma_f32_16x16x32_bf16(af[mi], bfr[ni], acc[mi][ni], 0, 0, 0);
    }
  }

  #pragma unroll
  for (int mi = 0; mi < 4; mi++) {
    #pragma unroll
    for (int rr = 0; rr < 4; rr++) {
      int m = row0 + wr * 64 + mi * 16 + lg * 4 + rr;
      float* cp = Cout + (size_t)m * N + col0 + wc * 64 + lm;
      #pragma unroll
      for (int ni = 0; ni < 4; ni++) cp[ni * 16] += acc[mi][ni][rr];
    }
  }
}

// ---------------- MFMA flash attention (bf16 I/O, defer-max, KVBLK=32) ----------------
__global__ __launch_bounds__(256) void attn_mfma(const unsigned short* __restrict__ qkv,
                                                 unsigned short* __restrict__ ao) {
  __shared__ alignas(16) char smem[20480];
  char* Ks = smem;
  char* Vt = smem + 4096;
  char* Pb = smem + 12288;

  int t = threadIdx.x, w = t >> 6, lane = t & 63, lm = lane & 15, lg = lane >> 4;
  int qt = blockIdx.x, bh = blockIdx.y, b = bh >> 4, h = bh & 15;
  const unsigned short* base = qkv + (size_t)b * T * C3;

  bf16x8 qf[2];
  {
    int qrow = qt * 64 + w * 16 + lm;
    const unsigned short* qp = base + (size_t)qrow * C3 + h * HD + lg * 8;
    qf[0] = *(const bf16x8*)qp;
    qf[1] = *(const bf16x8*)(qp + 32);
  }

  f32x4 o[4];
  #pragma unroll
  for (int i = 0; i < 4; i++) o[i] = f32x4{0.f, 0.f, 0.f, 0.f};
  float mrun[4] = {-INFINITY, -INFINITY, -INFINITY, -INFINITY};
  float lpart[4] = {0.f, 0.f, 0.f, 0.f};

  int ksrow = t >> 3, kc = (t & 7) * 8;
  int vdl = t & 7;
  bf16x8 kreg;
  unsigned short vv[8];
  auto LOADKV = [&](int s0) {
    kreg = *(const bf16x8*)(base + (size_t)(s0 + ksrow) * C3 + C + h * HD + kc);
    const unsigned short* vp = base + (size_t)(s0 + ksrow) * C3 + 2 * C + h * HD + vdl;
    #pragma unroll
    for (int i = 0; i < 8; i++) vv[i] = vp[8 * i];
  };

  LOADKV(0);
  for (int s0 = 0; s0 < T; s0 += 32) {
    __syncthreads();
    *(bf16x8*)(Ks + SWZ(ksrow, kc * 2)) = kreg;
    #pragma unroll
    for (int i = 0; i < 8; i++) {
      int d = 8 * i + vdl;
      *(short*)(Vt + (d << 7) + ((ksrow * 2) ^ ((d & 7) << 4))) = (short)vv[i];
    }
    __syncthreads();
    if (s0 + 32 < T) LOADKV(s0 + 32);

    f32x4 sacc[2];
    sacc[0] = f32x4{0.f, 0.f, 0.f, 0.f};
    sacc[1] = f32x4{0.f, 0.f, 0.f, 0.f};
    #pragma unroll
    for (int ni = 0; ni < 2; ni++)
      #pragma unroll
      for (int ks = 0; ks < 2; ks++) {
        bf16x8 kfrag = *(const bf16x8*)(Ks + SWZ(ni * 16 + lm, ks * 64 + lg * 16));
        sacc[ni] = __builtin_amdgcn_mfma_f32_16x16x32_bf16(qf[ks], kfrag, sacc[ni], 0, 0, 0);
      }

    float sv0[4], sv1[4], pv[8];
    bool okd = true;
    #pragma unroll
    for (int r = 0; r < 4; r++) {
      sv0[r] = sacc[0][r] * 0.125f;
      sv1[r] = sacc[1][r] * 0.125f;
      okd = okd && (fmaxf(sv0[r], sv1[r]) <= mrun[r] + 8.f);
    }
    if (__all(okd ? 1 : 0)) {
      #pragma unroll
      for (int r = 0; r < 4; r++) {
        float p0 = __expf(sv0[r] - mrun[r]);
        float p1 = __expf(sv1[r] - mrun[r]);
        lpart[r] += p0 + p1;
        pv[r] = p0; pv[4 + r] = p1;
      }
    } else {
      float fr[4];
      #pragma unroll
      for (int r = 0; r < 4; r++) {
        float tmax = fmaxf(sv0[r], sv1[r]);
        #pragma unroll
        for (int mk = 1; mk < 16; mk <<= 1) tmax = fmaxf(tmax, __shfl_xor(tmax, mk));
        float mn = fmaxf(mrun[r], tmax);
        float f = __expf(mrun[r] - mn);
        float p0 = __expf(sv0[r] - mn), p1 = __expf(sv1[r] - mn);
        lpart[r] = lpart[r] * f + p0 + p1;
        mrun[r] = mn;
        fr[r] = f;
        pv[r] = p0; pv[4 + r] = p1;
      }
      #pragma unroll
      for (int ni = 0; ni < 4; ni++) {
        o[ni][0] *= fr[0]; o[ni][1] *= fr[1]; o[ni][2] *= fr[2]; o[ni][3] *= fr[3];
      }
    }

    char* P = Pb + w * 2048;
    #pragma unroll
    for (int ni = 0; ni < 2; ni++)
      #pragma unroll
      for (int r = 0; r < 4; r++) {
        int q = lg * 4 + r;
        int kbyte = (ni * 16 + lm) * 2;
        *(short*)(P + (q << 7) + (kbyte ^ ((q & 7) << 4))) = f2b(pv[ni * 4 + r]);
      }
    bf16x8 pfrag = *(const bf16x8*)(P + SWZ(lm, lg * 16));
    #pragma unroll
    for (int ni = 0; ni < 4; ni++) {
      bf16x8 vfrag = *(const bf16x8*)(Vt + SWZ(ni * 16 + lm, lg * 16));
      o[ni] = __builtin_amdgcn_mfma_f32_16x16x32_bf16(pfrag, vfrag, o[ni], 0, 0, 0);
    }
  }

  float inv[4];
  #pragma unroll
  for (int r = 0; r < 4; r++) {
    float lsum = lpart[r];
    #pragma unroll
    for (int mk = 1; mk < 16; mk <<= 1) lsum += __shfl_xor(lsum, mk);
    inv[r] = 1.f / lsum;
  }
  #pragma unroll
  for (int r = 0; r < 4; r++) {
    int qrow = qt * 64 + w * 16 + lg * 4 + r;
    unsigned short* dst = ao + (size_t)(b * T + qrow) * C + h * HD + lm;
    #pragma unroll
    for (int ni = 0; ni < 4; ni++) dst[ni * 16] = (unsigned short)f2b(o[ni][r] * inv[r]);
  }
}

// ---------------- capacity assignment (software-pipelined) ----------------
__global__ __launch_bounds__(512) void capacity_kernel(
    const int* __restrict__ i0, const int* __restrict__ i1,
    const float* __restrict__ g0, const float* __restrict__ g1,
    int* __restrict__ sel, float* __restrict__ gsel, int* __restrict__ counts,
    int* __restrict__ slot0, int* __restrict__ slot1)
{
  int e = threadIdx.x >> 6, lane = threadIdx.x & 63;
  int cnt = 0;
  unsigned long long ltmask = (lane == 0) ? 0ull : (~0ull >> (64 - lane));
  int a = i0[lane], bb = i1[lane];
  for (int basei = 0; basei < NTOK; basei += 64) {
    int na = 0, nb = 0;
    if (basei + 64 < NTOK) { na = i0[basei + 64 + lane]; nb = i1[basei + 64 + lane]; }
    int tt = basei + lane;
    bool match = (a == e) || (bb == e);
    unsigned long long mk = __ballot(match);
    int pos = cnt + __popcll(mk & ltmask);
    if (match && pos < CAP) {
      sel[e * CAP + pos] = tt;
      gsel[e * CAP + pos] = (a == e) ? g0[tt] : g1[tt];
      if (a == e) slot0[tt] = e * CAP + pos;
      else        slot1[tt] = e * CAP + pos;
    }
    cnt += __popcll(mk);
    a = na; bb = nb;
  }
  if (lane == 0) counts[e] = cnt < CAP ? cnt : CAP;
}

// ---------------- head ----------------
__global__ __launch_bounds__(256) void head_part(const float* __restrict__ xin,
    const float* __restrict__ hw, float* __restrict__ partial)
{
  __shared__ float red[8];
  int blk = blockIdx.x;
  int b = blk >> 4, j = blk & 15;
  int tid = threadIdx.x;
  float4 wv = ((const float4*)hw)[tid];
  float s = 0.f;
  int t0 = j * 64;
  for (int t = t0; t < t0 + 64; t++) {
    float4 v = ((const float4*)(xin + (size_t)(b * T + t) * C))[tid];
    s += v.x * wv.x + v.y * wv.y + v.z * wv.z + v.w * wv.w;
  }
  #pragma unroll
  for (int off = 32; off > 0; off >>= 1) s += __shfl_down(s, off);
  if ((tid & 63) == 0) red[tid >> 6] = s;
  __syncthreads();
  if (tid == 0) partial[blk] = red[0] + red[1] + red[2] + red[3];
}

__global__ __launch_bounds__(64) void head_final(const float* __restrict__ partial,
    const float* __restrict__ hb, float* __restrict__ out)
{
  int tid = threadIdx.x;
  float v = partial[tid];
  #pragma unroll
  for (int off = 8; off > 0; off >>= 1) v += __shfl_down(v, off, 16);
  if ((tid & 15) == 0) out[tid >> 4] = v * (1.f / T) + hb[0];
}

}  // namespace

extern "C" void kernel_launch(void* const* d_in, const int* in_sizes, int n_in,
                              void* d_out, int out_size, void* d_ws, size_t ws_size,
                              hipStream_t stream) {
  (void)in_sizes; (void)n_in; (void)out_size; (void)ws_size;
  const int*   ids     = (const int*)d_in[0];
  const float* noise   = (const float*)d_in[1];
  const float* tok_emb = (const float*)d_in[2];
  const float* pos_emb = (const float*)d_in[3];
  const float* ln1_w   = (const float*)d_in[4];
  const float* ln1_b   = (const float*)d_in[5];
  const float* qkv_w   = (const float*)d_in[6];
  const float* out_w   = (const float*)d_in[7];
  const float* ln2_w   = (const float*)d_in[8];
  const float* ln2_b   = (const float*)d_in[9];
  const float* rt_w    = (const float*)d_in[10];
  const float* rt_b    = (const float*)d_in[11];
  const float* nz_w    = (const float*)d_in[12];
  const float* nz_b    = (const float*)d_in[13];
  const float* e_w1    = (const float*)d_in[14];
  const float* e_b1    = (const float*)d_in[15];
  const float* e_w2    = (const float*)d_in[16];
  const float* e_b2    = (const float*)d_in[17];
  const float* lnf_w   = (const float*)d_in[18];
  const float* lnf_b   = (const float*)d_in[19];
  const float* head_w  = (const float*)d_in[20];
  const float* head_b  = (const float*)d_in[21];
  float* out = (float*)d_out;

  char* wsp = (char*)d_ws;
  size_t off = 0;
  auto alloc = [&](size_t n) { char* p = wsp + off; off += (n + 255) & ~(size_t)255; return p; };
  float* x    = (float*)alloc((size_t)NTOK * C * 4);
  float* t1   = (float*)alloc((size_t)NTOK * C * 4);
  unsigned short* t1b  = (unsigned short*)alloc((size_t)NTOK * C * 2);
  unsigned short* qkvb = (unsigned short*)alloc((size_t)NTOK * C3 * 2);
  unsigned short* aob  = (unsigned short*)alloc((size_t)NTOK * C * 2);
  unsigned short* hbuf = (unsigned short*)alloc((size_t)E * CAP * C4 * 2);
  unsigned short* eo   = (unsigned short*)alloc((size_t)2 * E * CAP * C * 2);  // 2 K-slices
  unsigned short* qkvw_b = (unsigned short*)alloc((size_t)L * C3 * C * 2);
  unsigned short* outw_b = (unsigned short*)alloc((size_t)L * C * C * 2);
  int*   i0   = (int*)alloc(NTOK * 4);
  int*   i1   = (int*)alloc(NTOK * 4);
  float* g0   = (float*)alloc(NTOK * 4);
  float* g1   = (float*)alloc(NTOK * 4);
  int*   sel  = (int*)alloc(E * CAP * 4);
  float* gsel = (float*)alloc(E * CAP * 4);
  int*   counts = (int*)alloc(E * 4);
  int*   slot0  = (int*)alloc(NTOK * 4);
  int*   slot1  = (int*)alloc(NTOK * 4);
  float* hpart  = (float*)alloc(B * 16 * 4);

  // small conversion: qkv_w + out_w only
  {
    constexpr size_t TOT = (size_t)L * C3 * C + (size_t)L * C * C;
    cvt2_kernel<<<(int)(TOT / 4096), 256, 0, stream>>>(qkv_w, out_w, qkvw_b, outw_b);
  }

  for (int l = 0; l < L; l++) {
    if (l == 0)
      embed_ln_kernel<<<NTOK, 256, 0, stream>>>(ids, tok_emb, pos_emb, x, t1b,
                                                ln1_w, ln1_b);
    else
      ln_kernel<<<NTOK, 256, 0, stream>>>(x, eo, slot0, slot1, x,
                                          nullptr, t1b, ln1_w + l * C, ln1_b + l * C);
    gemm8p<false, false, false, false, 0, 1><<<dim3(C3 / 256, NTOK / 256), 512, 0, stream>>>(
        t1b, qkvw_b + (size_t)l * C3 * C, nullptr, qkvb,
        nullptr, nullptr, nullptr, NTOK, C3, C, 0, 0, 0, 0, 0);
    attn_mfma<<<dim3(T / 64, B * Hh), 256, 0, stream>>>(qkvb, aob);
    gemm_proj<<<dim3(C / 128, NTOK / 128), 256, 0, stream>>>(
        aob, outw_b + (size_t)l * C * C, x, NTOK, C, C);

    ln2_router_kernel<<<NTOK, 256, 0, stream>>>(x, t1b, ln2_w + l * C, ln2_b + l * C,
        rt_w + (size_t)l * E * C, rt_b + l * E, nz_w + (size_t)l * E * C, nz_b + l * E,
        noise + (size_t)l * NTOK * E, i0, i1, g0, g1, slot0, slot1);
    capacity_kernel<<<1, 512, 0, stream>>>(i0, i1, g0, g1, sel, gsel, counts, slot0, slot1);

    // grouped FFN1: fp32 W in-GEMM cvt, 128x256 depth-2 schedule
    gemm_wf32<true, true, true, 0, 1><<<E * (CAP / 128) * (C4 / 256), 512, 0, stream>>>(
        t1b, e_w1 + (size_t)l * E * C4 * C, e_b1 + (size_t)l * E * C4, hbuf,
        sel, nullptr, counts, CAP, C4, C,
        0, (size_t)C4 * C, (size_t)CAP * C4, C4, CAP / 128);
    // grouped FFN2 split-K=2: fp32 W in-GEMM cvt
    gemm_wf32<false, false, true, 2, 2><<<E * 2 * (CAP / 128) * (C / 256), 512, 0, stream>>>(
        hbuf, e_w2 + (size_t)l * E * C * C4, e_b2 + (size_t)l * E * C, eo,
        nullptr, gsel, counts, CAP, C, C4,
        (size_t)CAP * C4, (size_t)C * C4, 0, C, CAP / 128);
  }

  ln_kernel<<<NTOK, 256, 0, stream>>>(x, eo, slot0, slot1, nullptr,
                                      t1, nullptr, lnf_w, lnf_b);
  head_part<<<B * 16, 256, 0, stream>>>(t1, head_w, hpart);
  head_final<<<1, 64, 0, stream>>>(hpart, head_b, out);
}

// Round 15
// 825.702 us; speedup vs baseline: 1.4517x; 1.4517x over previous
//
#include <hip/hip_runtime.h>
#include <hip/hip_bf16.h>
#include <math.h>

namespace {

constexpr int B = 4, T = 1024, C = 1024, Hh = 16, L = 2, E = 8, HD = 64;
constexpr int NTOK = B * T;          // 4096
constexpr int CAP = 1024;            // B*T*K/E
constexpr int C3 = 3 * C, C4 = 4 * C;

typedef __attribute__((ext_vector_type(8))) short bf16x8;
typedef __attribute__((ext_vector_type(8))) short short8;
typedef __attribute__((ext_vector_type(4))) float f32x4;

static __device__ __forceinline__ short f2b(float f) {
  __hip_bfloat16 h = __float2bfloat16(f);
  return *reinterpret_cast<short*>(&h);
}
static __device__ __forceinline__ float b2f(unsigned short u) {
  union { unsigned int i; float f; } v; v.i = (unsigned int)u << 16; return v.f;
}

// swizzled byte offset within a tile of 128-byte rows (128^2 kernel / attn)
#define SWZ(row, kb) (((row) << 7) + ((kb) ^ (((row) & 7) << 4)))

static __device__ __forceinline__ void gload16(const void* g, void* l) {
  __builtin_amdgcn_global_load_lds((const __attribute__((address_space(1))) void*)g,
                                   (__attribute__((address_space(3))) void*)l, 16, 0, 0);
}

// ---------------- fused fp32 -> bf16 weight convert, one-shot (16 elem/thread) -------------
__global__ __launch_bounds__(256) void cvt4_kernel(
    const float* __restrict__ s0, const float* __restrict__ s1,
    const float* __restrict__ s2, const float* __restrict__ s3,
    unsigned short* __restrict__ d0, unsigned short* __restrict__ d1,
    unsigned short* __restrict__ d2, unsigned short* __restrict__ d3) {
  constexpr size_t N0 = (size_t)L * C3 * C, N1 = (size_t)L * C * C;
  constexpr size_t N2 = (size_t)L * E * C4 * C;
  size_t i = ((size_t)blockIdx.x * 256 + threadIdx.x) * 16;
  const float* s; unsigned short* d; size_t off;
  if (i < N0)                { s = s0; d = d0; off = i; }
  else if (i < N0 + N1)      { s = s1; d = d1; off = i - N0; }
  else if (i < N0 + N1 + N2) { s = s2; d = d2; off = i - N0 - N1; }
  else                       { s = s3; d = d3; off = i - N0 - N1 - N2; }
  float4 v0 = *(const float4*)(s + off);
  float4 v1 = *(const float4*)(s + off + 4);
  float4 v2 = *(const float4*)(s + off + 8);
  float4 v3 = *(const float4*)(s + off + 12);
  short8 r0, r1;
  r0[0] = f2b(v0.x); r0[1] = f2b(v0.y); r0[2] = f2b(v0.z); r0[3] = f2b(v0.w);
  r0[4] = f2b(v1.x); r0[5] = f2b(v1.y); r0[6] = f2b(v1.z); r0[7] = f2b(v1.w);
  r1[0] = f2b(v2.x); r1[1] = f2b(v2.y); r1[2] = f2b(v2.z); r1[3] = f2b(v2.w);
  r1[4] = f2b(v3.x); r1[5] = f2b(v3.y); r1[6] = f2b(v3.z); r1[7] = f2b(v3.w);
  *(short8*)(d + off) = r0;
  *(short8*)(d + off + 8) = r1;
}

// ------- fused embedding + ln1 (layer 0) -------
__global__ __launch_bounds__(256) void embed_ln_kernel(const int* __restrict__ ids,
    const float* __restrict__ tok, const float* __restrict__ pos,
    float* __restrict__ x, unsigned short* __restrict__ outb,
    const float* __restrict__ w, const float* __restrict__ b) {
  __shared__ float red[8];
  int row = blockIdx.x, tid = threadIdx.x;
  int t = row & (T - 1);
  int id = ids[row];
  float4 a = ((const float4*)(tok + (size_t)id * C))[tid];
  float4 p = ((const float4*)(pos + (size_t)t * C))[tid];
  float4 v{a.x + p.x, a.y + p.y, a.z + p.z, a.w + p.w};
  ((float4*)(x + (size_t)row * C))[tid] = v;
  float s = v.x + v.y + v.z + v.w;
  #pragma unroll
  for (int off = 32; off > 0; off >>= 1) s += __shfl_down(s, off);
  if ((tid & 63) == 0) red[tid >> 6] = s;
  __syncthreads();
  float mean = (red[0] + red[1] + red[2] + red[3]) * (1.f / C);
  __syncthreads();
  float dx = v.x - mean, dy = v.y - mean, dz = v.z - mean, dw = v.w - mean;
  float sq = dx * dx + dy * dy + dz * dz + dw * dw;
  #pragma unroll
  for (int off = 32; off > 0; off >>= 1) sq += __shfl_down(sq, off);
  if ((tid & 63) == 0) red[tid >> 6] = sq;
  __syncthreads();
  float var = (red[0] + red[1] + red[2] + red[3]) * (1.f / C);
  float rs = rsqrtf(var + 1e-5f);
  float4 wc = ((const float4*)w)[tid];
  float4 bc = ((const float4*)b)[tid];
  short4 ob{f2b(dx * rs * wc.x + bc.x), f2b(dy * rs * wc.y + bc.y),
            f2b(dz * rs * wc.z + bc.z), f2b(dw * rs * wc.w + bc.w)};
  *(short4*)(outb + (size_t)row * C + tid * 4) = ob;
}

// ------- layernorm with fused MoE-combine (ln1 for l>0) ----
__global__ __launch_bounds__(256) void ln_kernel(const float* __restrict__ in,
    const unsigned short* __restrict__ eo, const int* __restrict__ slot0,
    const int* __restrict__ slot1, float* __restrict__ xupd,
    unsigned short* __restrict__ outb,
    const float* __restrict__ w, const float* __restrict__ b) {
  constexpr size_t SLICE = (size_t)E * CAP * C;
  __shared__ float red[8];
  int row = blockIdx.x, tid = threadIdx.x;
  float4 v = ((const float4*)(in + (size_t)row * C))[tid];
  {
    int s0 = slot0[row], s1 = slot1[row];
    auto addslot = [&](int s) {
      if (s < 0) return;
      const unsigned short* p0 = eo + (size_t)s * C + tid * 4;
      short4 u = *(const short4*)p0;
      short4 u2 = *(const short4*)(p0 + SLICE);
      v.x += b2f((unsigned short)u.x) + b2f((unsigned short)u2.x);
      v.y += b2f((unsigned short)u.y) + b2f((unsigned short)u2.y);
      v.z += b2f((unsigned short)u.z) + b2f((unsigned short)u2.z);
      v.w += b2f((unsigned short)u.w) + b2f((unsigned short)u2.w);
    };
    addslot(s0);
    addslot(s1);
    ((float4*)(xupd + (size_t)row * C))[tid] = v;
  }
  float s = v.x + v.y + v.z + v.w;
  #pragma unroll
  for (int off = 32; off > 0; off >>= 1) s += __shfl_down(s, off);
  if ((tid & 63) == 0) red[tid >> 6] = s;
  __syncthreads();
  float mean = (red[0] + red[1] + red[2] + red[3]) * (1.f / C);
  __syncthreads();
  float dx = v.x - mean, dy = v.y - mean, dz = v.z - mean, dw = v.w - mean;
  float sq = dx * dx + dy * dy + dz * dz + dw * dw;
  #pragma unroll
  for (int off = 32; off > 0; off >>= 1) sq += __shfl_down(sq, off);
  if ((tid & 63) == 0) red[tid >> 6] = sq;
  __syncthreads();
  float var = (red[0] + red[1] + red[2] + red[3]) * (1.f / C);
  float rs = rsqrtf(var + 1e-5f);
  float4 wc = ((const float4*)w)[tid];
  float4 bc = ((const float4*)b)[tid];
  short4 ob{f2b(dx * rs * wc.x + bc.x), f2b(dy * rs * wc.y + bc.y),
            f2b(dz * rs * wc.z + bc.z), f2b(dw * rs * wc.w + bc.w)};
  *(short4*)(outb + (size_t)row * C + tid * 4) = ob;
}

// ------- fused lnf + MoE-combine + head dot: rowdot[row] = LN(x+eo)·head_w ----
__global__ __launch_bounds__(256) void lnf_head_kernel(const float* __restrict__ in,
    const unsigned short* __restrict__ eo, const int* __restrict__ slot0,
    const int* __restrict__ slot1,
    const float* __restrict__ w, const float* __restrict__ b,
    const float* __restrict__ hw, float* __restrict__ rowdot) {
  constexpr size_t SLICE = (size_t)E * CAP * C;
  __shared__ float red[8];
  int row = blockIdx.x, tid = threadIdx.x;
  float4 v = ((const float4*)(in + (size_t)row * C))[tid];
  {
    int s0 = slot0[row], s1 = slot1[row];
    auto addslot = [&](int s) {
      if (s < 0) return;
      const unsigned short* p0 = eo + (size_t)s * C + tid * 4;
      short4 u = *(const short4*)p0;
      short4 u2 = *(const short4*)(p0 + SLICE);
      v.x += b2f((unsigned short)u.x) + b2f((unsigned short)u2.x);
      v.y += b2f((unsigned short)u.y) + b2f((unsigned short)u2.y);
      v.z += b2f((unsigned short)u.z) + b2f((unsigned short)u2.z);
      v.w += b2f((unsigned short)u.w) + b2f((unsigned short)u2.w);
    };
    addslot(s0);
    addslot(s1);
  }
  float s = v.x + v.y + v.z + v.w;
  #pragma unroll
  for (int off = 32; off > 0; off >>= 1) s += __shfl_down(s, off);
  if ((tid & 63) == 0) red[tid >> 6] = s;
  __syncthreads();
  float mean = (red[0] + red[1] + red[2] + red[3]) * (1.f / C);
  __syncthreads();
  float dx = v.x - mean, dy = v.y - mean, dz = v.z - mean, dw = v.w - mean;
  float sq = dx * dx + dy * dy + dz * dz + dw * dw;
  #pragma unroll
  for (int off = 32; off > 0; off >>= 1) sq += __shfl_down(sq, off);
  if ((tid & 63) == 0) red[tid >> 6] = sq;
  __syncthreads();
  float var = (red[0] + red[1] + red[2] + red[3]) * (1.f / C);
  float rs = rsqrtf(var + 1e-5f);
  float4 wc = ((const float4*)w)[tid];
  float4 bc = ((const float4*)b)[tid];
  float4 hv = ((const float4*)hw)[tid];
  float d = (dx * rs * wc.x + bc.x) * hv.x + (dy * rs * wc.y + bc.y) * hv.y
          + (dz * rs * wc.z + bc.z) * hv.z + (dw * rs * wc.w + bc.w) * hv.w;
  #pragma unroll
  for (int off = 32; off > 0; off >>= 1) d += __shfl_down(d, off);
  if ((tid & 63) == 0) red[tid >> 6] = d;
  __syncthreads();
  if (tid == 0) rowdot[row] = red[0] + red[1] + red[2] + red[3];
}

__global__ __launch_bounds__(256) void head_final(const float* __restrict__ rowdot,
    const float* __restrict__ hb, float* __restrict__ out) {
  __shared__ float red[4];
  int b = blockIdx.x, tid = threadIdx.x;
  const float* p = rowdot + (size_t)b * T;
  float s = p[tid] + p[tid + 256] + p[tid + 512] + p[tid + 768];
  #pragma unroll
  for (int off = 32; off > 0; off >>= 1) s += __shfl_down(s, off);
  if ((tid & 63) == 0) red[tid >> 6] = s;
  __syncthreads();
  if (tid == 0) out[b] = (red[0] + red[1] + red[2] + red[3]) * (1.f / T) + hb[0];
}

// ------- fused ln2 + router ----
__global__ __launch_bounds__(256) void ln2_router_kernel(const float* __restrict__ in,
    unsigned short* __restrict__ outb,
    const float* __restrict__ w, const float* __restrict__ b,
    const float* __restrict__ rt_w, const float* __restrict__ rt_b,
    const float* __restrict__ nz_w, const float* __restrict__ nz_b,
    const float* __restrict__ noise,
    int* __restrict__ i0, int* __restrict__ i1, float* __restrict__ g0,
    float* __restrict__ g1, int* __restrict__ slot0, int* __restrict__ slot1)
{
  __shared__ float red[8];
  __shared__ float racc[4][16];
  int row = blockIdx.x, tid = threadIdx.x;
  float4 v = ((const float4*)(in + (size_t)row * C))[tid];
  float s = v.x + v.y + v.z + v.w;
  #pragma unroll
  for (int off = 32; off > 0; off >>= 1) s += __shfl_down(s, off);
  if ((tid & 63) == 0) red[tid >> 6] = s;
  __syncthreads();
  float mean = (red[0] + red[1] + red[2] + red[3]) * (1.f / C);
  __syncthreads();
  float dx = v.x - mean, dy = v.y - mean, dz = v.z - mean, dw = v.w - mean;
  float sq = dx * dx + dy * dy + dz * dz + dw * dw;
  #pragma unroll
  for (int off = 32; off > 0; off >>= 1) sq += __shfl_down(sq, off);
  if ((tid & 63) == 0) red[tid >> 6] = sq;
  __syncthreads();
  float var = (red[0] + red[1] + red[2] + red[3]) * (1.f / C);
  float rs = rsqrtf(var + 1e-5f);
  float4 wc = ((const float4*)w)[tid];
  float4 bc = ((const float4*)b)[tid];
  float4 o{dx * rs * wc.x + bc.x, dy * rs * wc.y + bc.y,
           dz * rs * wc.z + bc.z, dw * rs * wc.w + bc.w};
  short4 ob{f2b(o.x), f2b(o.y), f2b(o.z), f2b(o.w)};
  *(short4*)(outb + (size_t)row * C + tid * 4) = ob;

  float loc[16];
  #pragma unroll
  for (int e = 0; e < 8; e++) {
    float4 rw = *(const float4*)(rt_w + (size_t)e * C + tid * 4);
    float4 nw = *(const float4*)(nz_w + (size_t)e * C + tid * 4);
    loc[e]     = o.x * rw.x + o.y * rw.y + o.z * rw.z + o.w * rw.w;
    loc[8 + e] = o.x * nw.x + o.y * nw.y + o.z * nw.z + o.w * nw.w;
  }
  #pragma unroll
  for (int e = 0; e < 16; e++) {
    #pragma unroll
    for (int off = 32; off > 0; off >>= 1) loc[e] += __shfl_down(loc[e], off);
  }
  if ((tid & 63) == 0) {
    #pragma unroll
    for (int e = 0; e < 16; e++) racc[tid >> 6][e] = loc[e];
  }
  __syncthreads();
  if (tid == 0) {
    float nv[8];
    #pragma unroll
    for (int e = 0; e < 8; e++) {
      float lgt = racc[0][e] + racc[1][e] + racc[2][e] + racc[3][e] + rt_b[e];
      float nl = racc[0][8 + e] + racc[1][8 + e] + racc[2][8 + e] + racc[3][8 + e] + nz_b[e];
      float sp = fmaxf(nl, 0.f) + log1pf(expf(-fabsf(nl)));
      nv[e] = lgt + noise[(size_t)row * E + e] * sp;
    }
    float v0 = -INFINITY, v1 = -INFINITY; int b0 = -1, b1 = -1;
    #pragma unroll
    for (int e = 0; e < 8; e++) {
      float vv = nv[e];
      if (vv > v0)      { v1 = v0; b1 = b0; v0 = vv; b0 = e; }
      else if (vv > v1) { v1 = vv; b1 = e; }
    }
    float ex = expf(v1 - v0);
    float inv = 1.f / (1.f + ex);
    i0[row] = b0; i1[row] = b1;
    g0[row] = inv; g1[row] = ex * inv;
    slot0[row] = -1; slot1[row] = -1;
  }
}

// ============ 256x256 8-phase bf16 MFMA GEMM (T3+T4+T5), optional split-K ============
template<bool GATHER, bool RELU, bool BIAS, bool XCDMAP, int OUTMODE, int SPLITK>
__global__ __launch_bounds__(512, 2) void gemm8p(
    const unsigned short* __restrict__ A, const unsigned short* __restrict__ W,
    const float* __restrict__ bias, unsigned short* __restrict__ Cout,
    const int* __restrict__ rowidx, const float* __restrict__ rowscale,
    const int* __restrict__ cnts, int M, int N, int Kd,
    size_t strideA, size_t strideW, size_t strideOut, int strideBias, int GY)
{
  __shared__ alignas(16) char smem[131072];
  int bx, by, e, ksl;
  if constexpr (XCDMAP) {
    int fid = blockIdx.x; e = fid & 7; int r1 = fid >> 3;
    ksl = r1 & (SPLITK - 1); int wi = r1 / SPLITK;
    by = wi % GY; bx = wi / GY;
  } else { bx = blockIdx.x; by = blockIdx.y; e = 0; ksl = 0; }
  int Mr = M;
  if (cnts) { int cc = cnts[e]; Mr = cc < M ? cc : M; }
  int row0 = by * 256, col0 = bx * 256;
  if (row0 >= Mr) return;

  const int kLen = Kd / SPLITK;
  const unsigned short* Ap = A + (size_t)e * strideA;
  const unsigned short* Wp = W + (size_t)e * strideW;
  const int* ridx = rowidx ? rowidx + (size_t)e * CAP : nullptr;

  int t = threadIdx.x;
  int l = t & 63, lm = l & 15, lg = l >> 4;
  int w = t >> 6, wm = w >> 2, wn = w & 3;

  const char* srcA[2];
  const char* srcB[2];
  #pragma unroll
  for (int j = 0; j < 2; j++) {
    int flat = t + j * 512;
    int row = flat >> 2;
    int c16 = (flat & 3) ^ ((row >> 1) & 3);
    int ga;
    if constexpr (GATHER) {
      int ar = row0 + row; if (ar >= Mr) ar = Mr - 1; ga = ridx[ar];
    } else ga = row0 + row;
    srcA[j] = (const char*)Ap + (size_t)ga * Kd * 2 + (size_t)ksl * kLen * 2 + c16 * 16;
    srcB[j] = (const char*)Wp + (size_t)(col0 + row) * Kd * 2 + (size_t)ksl * kLen * 2 + c16 * 16;
  }
  int dst0 = t * 16, dst1 = t * 16 + 8192;

  auto STAGE = [&](int buf, int op, int kh, int kt) {
    size_t goff = (size_t)kt * 128 + kh * 64;
    char* base = smem + buf * 65536 + op * 32768 + kh * 16384;
    if (op) {
      gload16(srcB[0] + goff, base + dst0);
      gload16(srcB[1] + goff, base + dst1);
    } else {
      gload16(srcA[0] + goff, base + dst0);
      gload16(srcA[1] + goff, base + dst1);
    }
  };

  int colswz = (lg ^ ((lm >> 1) & 3)) * 16;

  f32x4 acc[8][4];
  #pragma unroll
  for (int i = 0; i < 8; i++)
    #pragma unroll
    for (int j = 0; j < 4; j++) acc[i][j] = f32x4{0.f, 0.f, 0.f, 0.f};

  STAGE(0, 0, 0, 0); STAGE(0, 1, 0, 0); STAGE(0, 0, 1, 0); STAGE(0, 1, 1, 0);
  asm volatile("s_waitcnt vmcnt(0)" ::: "memory");
  __builtin_amdgcn_s_barrier();

  int NT = kLen >> 6;
  bf16x8 bfr[4];
  for (int k = 0; k < NT; k++) {
    int cur = k & 1, nxt = cur ^ 1;
    bool pf = (k + 1 < NT);
    #pragma unroll
    for (int ph = 0; ph < 4; ph++) {
      const int ks = ph >> 1, mh = ph & 1;
      bf16x8 afr[4];
      #pragma unroll
      for (int i = 0; i < 4; i++) {
        int row = wm * 128 + (mh * 4 + i) * 16 + lm;
        afr[i] = *(const bf16x8*)(smem + cur * 65536 + ks * 16384 + row * 64 + colswz);
      }
      if (mh == 0) {
        #pragma unroll
        for (int i = 0; i < 4; i++) {
          int row = wn * 64 + i * 16 + lm;
          bfr[i] = *(const bf16x8*)(smem + cur * 65536 + 32768 + ks * 16384 + row * 64 + colswz);
        }
      }
      if (pf) STAGE(nxt, mh, ks, k + 1);   // ph0:A-kh0 ph1:B-kh0 ph2:A-kh1 ph3:B-kh1
      if (mh == 1) {
        if (pf) asm volatile("s_waitcnt vmcnt(4)" ::: "memory");
        else    asm volatile("s_waitcnt vmcnt(0)" ::: "memory");
      }
      __builtin_amdgcn_s_barrier();
      __builtin_amdgcn_s_setprio(1);
      #pragma unroll
      for (int i = 0; i < 4; i++)
        #pragma unroll
        for (int ni = 0; ni < 4; ni++)
          acc[mh * 4 + i][ni] =
              __builtin_amdgcn_mfma_f32_16x16x32_bf16(afr[i], bfr[ni], acc[mh * 4 + i][ni], 0, 0, 0);
      __builtin_amdgcn_s_setprio(0);
      __builtin_amdgcn_s_barrier();
    }
  }

  float cbias[4];
  #pragma unroll
  for (int ni = 0; ni < 4; ni++)
    cbias[ni] = (BIAS && ksl == 0) ? bias[(size_t)e * strideBias + col0 + wn * 64 + ni * 16 + lm] : 0.f;

  #pragma unroll
  for (int mi = 0; mi < 8; mi++) {
    #pragma unroll
    for (int rr = 0; rr < 4; rr++) {
      int m = row0 + wm * 128 + mi * 16 + lg * 4 + rr;
      if (m >= Mr) continue;
      if constexpr (OUTMODE == 0) {
        unsigned short* cp = Cout + (size_t)e * strideOut + (size_t)m * N + col0 + wn * 64 + lm;
        #pragma unroll
        for (int ni = 0; ni < 4; ni++) {
          float v = acc[mi][ni][rr] + cbias[ni];
          if constexpr (RELU) v = fmaxf(v, 0.f);
          cp[ni * 16] = (unsigned short)f2b(v);
        }
      } else {
        float sc = rowscale[(size_t)e * CAP + m];
        unsigned short* cp = Cout + (size_t)ksl * ((size_t)E * CAP * N)
                             + ((size_t)e * CAP + m) * N + col0 + wn * 64 + lm;
        #pragma unroll
        for (int ni = 0; ni < 4; ni++) {
          float v = acc[mi][ni][rr] + cbias[ni];
          cp[ni * 16] = (unsigned short)f2b(sc * v);
        }
      }
    }
  }
}

// ---------------- 128^2 bf16 MFMA GEMM (proj, fp32 residual accumulate) ----------------
__global__ __launch_bounds__(256) void gemm_proj(
    const unsigned short* __restrict__ A, const unsigned short* __restrict__ W,
    float* __restrict__ Cout, int M, int N, int Kd)
{
  int bx = blockIdx.x, by = blockIdx.y;
  int row0 = by * 128, col0 = bx * 128;

  __shared__ alignas(16) char smem[32768];
  char* Ab = smem;
  char* Bb = smem + 16384;

  int t = threadIdx.x, w = t >> 6, l = t & 63;
  int lm = l & 15, lg = l >> 4;
  int wr = w >> 1, wc = w & 1;

  int lrow8 = l >> 3;
  int scol = ((l & 7) ^ lrow8) << 4;
  const char* srcA[4];
  const char* srcB[4];
  #pragma unroll
  for (int i = 0; i < 4; i++) {
    int seg = w * 4 + i;
    int rloc = seg * 8 + lrow8;
    srcA[i] = (const char*)A + (size_t)(row0 + rloc) * Kd * 2 + scol;
    srcB[i] = (const char*)W + (size_t)(col0 + rloc) * Kd * 2 + scol;
  }

  f32x4 acc[4][4];
  #pragma unroll
  for (int i = 0; i < 4; i++)
    #pragma unroll
    for (int j = 0; j < 4; j++) acc[i][j] = f32x4{0.f, 0.f, 0.f, 0.f};

  int NT = Kd >> 6;
  for (int kt = 0; kt < NT; kt++) {
    __syncthreads();
    #pragma unroll
    for (int i = 0; i < 4; i++) {
      int seg = w * 4 + i;
      gload16(srcA[i], Ab + seg * 1024);
      gload16(srcB[i], Bb + seg * 1024);
      srcA[i] += 128;
      srcB[i] += 128;
    }
    __syncthreads();
    #pragma unroll
    for (int ks = 0; ks < 2; ks++) {
      bf16x8 af[4], bfr[4];
      #pragma unroll
      for (int mi = 0; mi < 4; mi++)
        af[mi] = *(const bf16x8*)(Ab + SWZ(wr * 64 + mi * 16 + lm, ks * 64 + lg * 16));
      #pragma unroll
      for (int ni = 0; ni < 4; ni++)
        bfr[ni] = *(const bf16x8*)(Bb + SWZ(wc * 64 + ni * 16 + lm, ks * 64 + lg * 16));
      #pragma unroll
      for (int mi = 0; mi < 4; mi++)
        #pragma unroll
        for (int ni = 0; ni < 4; ni++)
          acc[mi][ni] = __builtin_amdgcn_mfma_f32_16x16x32_bf16(af[mi], bfr[ni], acc[mi][ni], 0, 0, 0);
    }
  }

  #pragma unroll
  for (int mi = 0; mi < 4; mi++) {
    #pragma unroll
    for (int rr = 0; rr < 4; rr++) {
      int m = row0 + wr * 64 + mi * 16 + lg * 4 + rr;
      float* cp = Cout + (size_t)m * N + col0 + wc * 64 + lm;
      #pragma unroll
      for (int ni = 0; ni < 4; ni++) cp[ni * 16] += acc[mi][ni][rr];
    }
  }
}

// ---------------- MFMA flash attention (bf16 I/O, defer-max, KVBLK=32) ----------------
__global__ __launch_bounds__(256) void attn_mfma(const unsigned short* __restrict__ qkv,
                                                 unsigned short* __restrict__ ao) {
  __shared__ alignas(16) char smem[20480];
  char* Ks = smem;
  char* Vt = smem + 4096;
  char* Pb = smem + 12288;

  int t = threadIdx.x, w = t >> 6, lane = t & 63, lm = lane & 15, lg = lane >> 4;
  int qt = blockIdx.x, bh = blockIdx.y, b = bh >> 4, h = bh & 15;
  const unsigned short* base = qkv + (size_t)b * T * C3;

  bf16x8 qf[2];
  {
    int qrow = qt * 64 + w * 16 + lm;
    const unsigned short* qp = base + (size_t)qrow * C3 + h * HD + lg * 8;
    qf[0] = *(const bf16x8*)qp;
    qf[1] = *(const bf16x8*)(qp + 32);
  }

  f32x4 o[4];
  #pragma unroll
  for (int i = 0; i < 4; i++) o[i] = f32x4{0.f, 0.f, 0.f, 0.f};
  float mrun[4] = {-INFINITY, -INFINITY, -INFINITY, -INFINITY};
  float lpart[4] = {0.f, 0.f, 0.f, 0.f};

  int ksrow = t >> 3, kc = (t & 7) * 8;
  int vdl = t & 7;
  bf16x8 kreg;
  unsigned short vv[8];
  auto LOADKV = [&](int s0) {
    kreg = *(const bf16x8*)(base + (size_t)(s0 + ksrow) * C3 + C + h * HD + kc);
    const unsigned short* vp = base + (size_t)(s0 + ksrow) * C3 + 2 * C + h * HD + vdl;
    #pragma unroll
    for (int i = 0; i < 8; i++) vv[i] = vp[8 * i];
  };

  LOADKV(0);
  for (int s0 = 0; s0 < T; s0 += 32) {
    __syncthreads();
    *(bf16x8*)(Ks + SWZ(ksrow, kc * 2)) = kreg;
    #pragma unroll
    for (int i = 0; i < 8; i++) {
      int d = 8 * i + vdl;
      *(short*)(Vt + (d << 7) + ((ksrow * 2) ^ ((d & 7) << 4))) = (short)vv[i];
    }
    __syncthreads();
    if (s0 + 32 < T) LOADKV(s0 + 32);

    f32x4 sacc[2];
    sacc[0] = f32x4{0.f, 0.f, 0.f, 0.f};
    sacc[1] = f32x4{0.f, 0.f, 0.f, 0.f};
    #pragma unroll
    for (int ni = 0; ni < 2; ni++)
      #pragma unroll
      for (int ks = 0; ks < 2; ks++) {
        bf16x8 kfrag = *(const bf16x8*)(Ks + SWZ(ni * 16 + lm, ks * 64 + lg * 16));
        sacc[ni] = __builtin_amdgcn_mfma_f32_16x16x32_bf16(qf[ks], kfrag, sacc[ni], 0, 0, 0);
      }

    float sv0[4], sv1[4], pv[8];
    bool okd = true;
    #pragma unroll
    for (int r = 0; r < 4; r++) {
      sv0[r] = sacc[0][r] * 0.125f;
      sv1[r] = sacc[1][r] * 0.125f;
      okd = okd && (fmaxf(sv0[r], sv1[r]) <= mrun[r] + 8.f);
    }
    if (__all(okd ? 1 : 0)) {
      #pragma unroll
      for (int r = 0; r < 4; r++) {
        float p0 = __expf(sv0[r] - mrun[r]);
        float p1 = __expf(sv1[r] - mrun[r]);
        lpart[r] += p0 + p1;
        pv[r] = p0; pv[4 + r] = p1;
      }
    } else {
      float fr[4];
      #pragma unroll
      for (int r = 0; r < 4; r++) {
        float tmax = fmaxf(sv0[r], sv1[r]);
        #pragma unroll
        for (int mk = 1; mk < 16; mk <<= 1) tmax = fmaxf(tmax, __shfl_xor(tmax, mk));
        float mn = fmaxf(mrun[r], tmax);
        float f = __expf(mrun[r] - mn);
        float p0 = __expf(sv0[r] - mn), p1 = __expf(sv1[r] - mn);
        lpart[r] = lpart[r] * f + p0 + p1;
        mrun[r] = mn;
        fr[r] = f;
        pv[r] = p0; pv[4 + r] = p1;
      }
      #pragma unroll
      for (int ni = 0; ni < 4; ni++) {
        o[ni][0] *= fr[0]; o[ni][1] *= fr[1]; o[ni][2] *= fr[2]; o[ni][3] *= fr[3];
      }
    }

    char* P = Pb + w * 2048;
    #pragma unroll
    for (int ni = 0; ni < 2; ni++)
      #pragma unroll
      for (int r = 0; r < 4; r++) {
        int q = lg * 4 + r;
        int kbyte = (ni * 16 + lm) * 2;
        *(short*)(P + (q << 7) + (kbyte ^ ((q & 7) << 4))) = f2b(pv[ni * 4 + r]);
      }
    bf16x8 pfrag = *(const bf16x8*)(P + SWZ(lm, lg * 16));
    #pragma unroll
    for (int ni = 0; ni < 4; ni++) {
      bf16x8 vfrag = *(const bf16x8*)(Vt + SWZ(ni * 16 + lm, lg * 16));
      o[ni] = __builtin_amdgcn_mfma_f32_16x16x32_bf16(pfrag, vfrag, o[ni], 0, 0, 0);
    }
  }

  float inv[4];
  #pragma unroll
  for (int r = 0; r < 4; r++) {
    float lsum = lpart[r];
    #pragma unroll
    for (int mk = 1; mk < 16; mk <<= 1) lsum += __shfl_xor(lsum, mk);
    inv[r] = 1.f / lsum;
  }
  #pragma unroll
  for (int r = 0; r < 4; r++) {
    int qrow = qt * 64 + w * 16 + lg * 4 + r;
    unsigned short* dst = ao + (size_t)(b * T + qrow) * C + h * HD + lm;
    #pragma unroll
    for (int ni = 0; ni < 4; ni++) dst[ni * 16] = (unsigned short)f2b(o[ni][r] * inv[r]);
  }
}

// ---------------- capacity assignment (software-pipelined) ----------------
__global__ __launch_bounds__(512) void capacity_kernel(
    const int* __restrict__ i0, const int* __restrict__ i1,
    const float* __restrict__ g0, const float* __restrict__ g1,
    int* __restrict__ sel, float* __restrict__ gsel, int* __restrict__ counts,
    int* __restrict__ slot0, int* __restrict__ slot1)
{
  int e = threadIdx.x >> 6, lane = threadIdx.x & 63;
  int cnt = 0;
  unsigned long long ltmask = (lane == 0) ? 0ull : (~0ull >> (64 - lane));
  int a = i0[lane], bb = i1[lane];
  for (int basei = 0; basei < NTOK; basei += 64) {
    int na = 0, nb = 0;
    if (basei + 64 < NTOK) { na = i0[basei + 64 + lane]; nb = i1[basei + 64 + lane]; }
    int tt = basei + lane;
    bool match = (a == e) || (bb == e);
    unsigned long long mk = __ballot(match);
    int pos = cnt + __popcll(mk & ltmask);
    if (match && pos < CAP) {
      sel[e * CAP + pos] = tt;
      gsel[e * CAP + pos] = (a == e) ? g0[tt] : g1[tt];
      if (a == e) slot0[tt] = e * CAP + pos;
      else        slot1[tt] = e * CAP + pos;
    }
    cnt += __popcll(mk);
    a = na; bb = nb;
  }
  if (lane == 0) counts[e] = cnt < CAP ? cnt : CAP;
}

}  // namespace

extern "C" void kernel_launch(void* const* d_in, const int* in_sizes, int n_in,
                              void* d_out, int out_size, void* d_ws, size_t ws_size,
                              hipStream_t stream) {
  (void)in_sizes; (void)n_in; (void)out_size; (void)ws_size;
  const int*   ids     = (const int*)d_in[0];
  const float* noise   = (const float*)d_in[1];
  const float* tok_emb = (const float*)d_in[2];
  const float* pos_emb = (const float*)d_in[3];
  const float* ln1_w   = (const float*)d_in[4];
  const float* ln1_b   = (const float*)d_in[5];
  const float* qkv_w   = (const float*)d_in[6];
  const float* out_w   = (const float*)d_in[7];
  const float* ln2_w   = (const float*)d_in[8];
  const float* ln2_b   = (const float*)d_in[9];
  const float* rt_w    = (const float*)d_in[10];
  const float* rt_b    = (const float*)d_in[11];
  const float* nz_w    = (const float*)d_in[12];
  const float* nz_b    = (const float*)d_in[13];
  const float* e_w1    = (const float*)d_in[14];
  const float* e_b1    = (const float*)d_in[15];
  const float* e_w2    = (const float*)d_in[16];
  const float* e_b2    = (const float*)d_in[17];
  const float* lnf_w   = (const float*)d_in[18];
  const float* lnf_b   = (const float*)d_in[19];
  const float* head_w  = (const float*)d_in[20];
  const float* head_b  = (const float*)d_in[21];
  float* out = (float*)d_out;

  char* wsp = (char*)d_ws;
  size_t off = 0;
  auto alloc = [&](size_t n) { char* p = wsp + off; off += (n + 255) & ~(size_t)255; return p; };
  float* x    = (float*)alloc((size_t)NTOK * C * 4);
  unsigned short* t1b  = (unsigned short*)alloc((size_t)NTOK * C * 2);
  unsigned short* qkvb = (unsigned short*)alloc((size_t)NTOK * C3 * 2);
  unsigned short* aob  = (unsigned short*)alloc((size_t)NTOK * C * 2);
  unsigned short* hbuf = (unsigned short*)alloc((size_t)E * CAP * C4 * 2);
  unsigned short* eo   = (unsigned short*)alloc((size_t)2 * E * CAP * C * 2);  // 2 K-slices
  unsigned short* qkvw_b = (unsigned short*)alloc((size_t)L * C3 * C * 2);
  unsigned short* outw_b = (unsigned short*)alloc((size_t)L * C * C * 2);
  unsigned short* ew1_b  = (unsigned short*)alloc((size_t)L * E * C4 * C * 2);
  unsigned short* ew2_b  = (unsigned short*)alloc((size_t)L * E * C * C4 * 2);
  int*   i0   = (int*)alloc(NTOK * 4);
  int*   i1   = (int*)alloc(NTOK * 4);
  float* g0   = (float*)alloc(NTOK * 4);
  float* g1   = (float*)alloc(NTOK * 4);
  int*   sel  = (int*)alloc(E * CAP * 4);
  float* gsel = (float*)alloc(E * CAP * 4);
  int*   counts = (int*)alloc(E * 4);
  int*   slot0  = (int*)alloc(NTOK * 4);
  int*   slot1  = (int*)alloc(NTOK * 4);
  float* rowdot = (float*)alloc(NTOK * 4);

  // single fused weight conversion (one-shot, 16 elem/thread)
  {
    constexpr size_t TOT = (size_t)L * C3 * C + (size_t)L * C * C + 2 * (size_t)L * E * C4 * C;
    cvt4_kernel<<<(int)(TOT / 4096), 256, 0, stream>>>(qkv_w, out_w, e_w1, e_w2,
                                                       qkvw_b, outw_b, ew1_b, ew2_b);
  }

  for (int l = 0; l < L; l++) {
    if (l == 0)
      embed_ln_kernel<<<NTOK, 256, 0, stream>>>(ids, tok_emb, pos_emb, x, t1b,
                                                ln1_w, ln1_b);
    else
      ln_kernel<<<NTOK, 256, 0, stream>>>(x, eo, slot0, slot1, x,
                                          t1b, ln1_w + l * C, ln1_b + l * C);
    gemm8p<false, false, false, false, 0, 1><<<dim3(C3 / 256, NTOK / 256), 512, 0, stream>>>(
        t1b, qkvw_b + (size_t)l * C3 * C, nullptr, qkvb,
        nullptr, nullptr, nullptr, NTOK, C3, C, 0, 0, 0, 0, 0);
    attn_mfma<<<dim3(T / 64, B * Hh), 256, 0, stream>>>(qkvb, aob);
    gemm_proj<<<dim3(C / 128, NTOK / 128), 256, 0, stream>>>(
        aob, outw_b + (size_t)l * C * C, x, NTOK, C, C);

    ln2_router_kernel<<<NTOK, 256, 0, stream>>>(x, t1b, ln2_w + l * C, ln2_b + l * C,
        rt_w + (size_t)l * E * C, rt_b + l * E, nz_w + (size_t)l * E * C, nz_b + l * E,
        noise + (size_t)l * NTOK * E, i0, i1, g0, g1, slot0, slot1);
    capacity_kernel<<<1, 512, 0, stream>>>(i0, i1, g0, g1, sel, gsel, counts, slot0, slot1);

    gemm8p<true, true, true, true, 0, 1><<<(C4 / 256) * (CAP / 256) * E, 512, 0, stream>>>(
        t1b, ew1_b + (size_t)l * E * C4 * C, e_b1 + (size_t)l * E * C4, hbuf,
        sel, nullptr, counts, CAP, C4, C,
        0, (size_t)C4 * C, (size_t)CAP * C4, C4, CAP / 256);
    gemm8p<false, false, true, true, 2, 2><<<(C / 256) * (CAP / 256) * 2 * E, 512, 0, stream>>>(
        hbuf, ew2_b + (size_t)l * E * C * C4, e_b2 + (size_t)l * E * C, eo,
        nullptr, gsel, counts, CAP, C, C4,
        (size_t)CAP * C4, (size_t)C * C4, 0, C, CAP / 256);
  }

  // fused: lnf + layer L-1 MoE combine + head dot, then tiny reduce
  lnf_head_kernel<<<NTOK, 256, 0, stream>>>(x, eo, slot0, slot1,
                                            lnf_w, lnf_b, head_w, rowdot);
  head_final<<<B, 256, 0, stream>>>(rowdot, head_b, out);
}